// Round 3
// baseline (314.455 us; speedup 1.0000x reference)
//
#include <hip/hip_runtime.h>
#include <cstdint>

#define IN_F   4096
#define OUT_F  14336
#define GROUP  128
#define KROT   8
#define BATCH  16
#define NJP    (OUT_F / 8)    // 1792 packed words per weight row
#define NG     (IN_F / GROUP) // 32 groups

// Rotated activations, fp32. Module-scope scratch (no d_ws dependence).
__device__ float g_xr[BATCH * IN_F];

// ---------------------------------------------------------------------------
// Kernel 1: rotation layers. One block per batch row (rows independent,
// layers sequential -> __syncthreads between layers). Each index appears in
// exactly one pair per layer (pairs[k] is a permutation) -> no races.
// Also zero-fills d_out (it is re-poisoned to 0xAA before every timed call).
// ---------------------------------------------------------------------------
__global__ __launch_bounds__(1024) void k_rotate(
    const float* __restrict__ x,      // [16][4096] f32 (fp16 promoted)
    const float* __restrict__ theta,  // [8][2048]  f32
    const int*   __restrict__ pairs,  // [8][4096]  int32
    const float* __restrict__ cscale, // [4096]     f32
    float*       __restrict__ outp)   // [16][14336] f32 = d_out
{
    __shared__ float row[IN_F];
    const int b   = blockIdx.x;
    const int tid = threadIdx.x;

    // zero d_out: 16 blocks x 1024 threads, 14 iters cover 229376 floats
    for (int i = b * 1024 + tid; i < BATCH * OUT_F; i += 16 * 1024)
        outp[i] = 0.0f;

    for (int i = tid; i < IN_F; i += 1024) row[i] = x[b * IN_F + i];
    __syncthreads();

    for (int k = 0; k < KROT; ++k) {
        const int2*  pk = (const int2*)(pairs + k * IN_F);
        const float* tk = theta + k * (IN_F / 2);
        for (int p = tid; p < IN_F / 2; p += 1024) {
            int2  ij = pk[p];
            float th = tk[p];
            float c = cosf(th), s = sinf(th);
            float a  = row[ij.x];
            float bb = row[ij.y];
            row[ij.x] = c * a - s * bb;
            row[ij.y] = s * a + c * bb;
        }
        __syncthreads();
    }

    for (int i = tid; i < IN_F; i += 1024)
        g_xr[b * IN_F + i] = row[i] * cscale[i];
}

// ---------------------------------------------------------------------------
// Kernel 2: dequant + GEMM. Block = (group g 0..31, 128-word jp chunk 0..13).
// Thread = (jp lane 0..127, batch-half 0..1): 8 cols x 8 batches fp32 acc.
// Each qweight word is loaded exactly once device-wide (coalesced 256B/wave)
// and unpacked once. 32 K-split partials reduce straight into d_out via HW
// fp32 atomics.
// ---------------------------------------------------------------------------
__global__ __launch_bounds__(256) void k_gemm(
    const int*   __restrict__ qweight, // [4096][1792] int32
    const int*   __restrict__ qzeros,  // [32][1792]   int32
    const float* __restrict__ scales,  // [32][14336]  f32
    float*       __restrict__ outp)    // [16][14336]  f32 = d_out (zeroed)
{
    __shared__ float xl[GROUP][BATCH];
    const int g   = blockIdx.x & 31;
    const int jpr = blockIdx.x >> 5;   // 0..13
    const int tid = threadIdx.x;

    // stage this K-group's activations: consecutive tid -> consecutive kk
    for (int idx = tid; idx < GROUP * BATCH; idx += 256) {
        int kk = idx & 127, b = idx >> 7;
        xl[kk][b] = g_xr[b * IN_F + g * GROUP + kk];
    }
    __syncthreads();

    const int jp = jpr * 128 + (tid & 127);  // packed-word column, 0..1791
    const int bh = tid >> 7;                 // batch half

    const uint32_t zw = (uint32_t)qzeros[g * NJP + jp];
    const float4* sc4 = (const float4*)(scales + (size_t)g * OUT_F + jp * 8);
    float4 s0 = sc4[0], s1 = sc4[1];
    float s[8] = {s0.x, s0.y, s0.z, s0.w, s1.x, s1.y, s1.z, s1.w};
    float o[8];
#pragma unroll
    for (int c = 0; c < 8; ++c)
        o[c] = (float)((zw >> (4 * c)) & 15u) * s[c];  // zero-point * scale

    float acc[8][8];
#pragma unroll
    for (int bb = 0; bb < 8; ++bb)
#pragma unroll
        for (int c = 0; c < 8; ++c) acc[bb][c] = 0.0f;

    const int* qw = qweight + (size_t)(g * GROUP) * NJP + jp;
    for (int kk = 0; kk < GROUP; ++kk) {
        uint32_t w = (uint32_t)qw[(size_t)kk * NJP];
        float wf[8];
#pragma unroll
        for (int c = 0; c < 8; ++c)
            wf[c] = fmaf((float)((w >> (4 * c)) & 15u), s[c], -o[c]);

        // all lanes of a wave read the same row -> LDS broadcast, no conflict
        const float4* xk = (const float4*)&xl[kk][bh * 8];
        float4 x0 = xk[0], x1 = xk[1];
        float  xv[8] = {x0.x, x0.y, x0.z, x0.w, x1.x, x1.y, x1.z, x1.w};
#pragma unroll
        for (int bb = 0; bb < 8; ++bb)
#pragma unroll
            for (int c = 0; c < 8; ++c)
                acc[bb][c] = fmaf(xv[bb], wf[c], acc[bb][c]);
    }

#pragma unroll
    for (int bb = 0; bb < 8; ++bb)
#pragma unroll
        for (int c = 0; c < 8; ++c)
            unsafeAtomicAdd(&outp[(size_t)(bh * 8 + bb) * OUT_F + jp * 8 + c],
                            acc[bb][c]);
}

extern "C" void kernel_launch(void* const* d_in, const int* in_sizes, int n_in,
                              void* d_out, int out_size, void* d_ws, size_t ws_size,
                              hipStream_t stream) {
    const float* x       = (const float*)d_in[0];
    const float* theta   = (const float*)d_in[1];
    const int*   pairs   = (const int*)d_in[2];
    const float* cscale  = (const float*)d_in[3];
    const int*   qweight = (const int*)d_in[4];
    const int*   qzeros  = (const int*)d_in[5];
    const float* scales  = (const float*)d_in[6];
    float*       out     = (float*)d_out;
    (void)d_ws; (void)ws_size;

    k_rotate<<<16, 1024, 0, stream>>>(x, theta, pairs, cscale, out);
    k_gemm<<<448, 256, 0, stream>>>(qweight, qzeros, scales, out);
}

// Round 4
// 142.951 us; speedup vs baseline: 2.1997x; 2.1997x over previous
//
#include <hip/hip_runtime.h>
#include <cstdint>

#define IN_F   4096
#define OUT_F  14336
#define GROUP  128
#define KROT   8
#define BATCH  16
#define NJP    (OUT_F / 8)    // 1792 packed words per weight row
#define NG     (IN_F / GROUP) // 32 groups

// Module-scope scratch (no d_ws dependence; fully rewritten every call).
__device__ float g_xr[BATCH * IN_F];                 // rotated activations
__device__ float g_part[NG * BATCH * OUT_F];         // 29.4 MB K-split partials

// ---------------------------------------------------------------------------
// Kernel 1: rotation layers. One block per batch row (rows independent,
// layers sequential). pairs[k] is a permutation -> no intra-layer races.
// ---------------------------------------------------------------------------
__global__ __launch_bounds__(1024) void k_rotate(
    const float* __restrict__ x,      // [16][4096] f32 (fp16 promoted)
    const float* __restrict__ theta,  // [8][2048]  f32
    const int*   __restrict__ pairs,  // [8][4096]  int32
    const float* __restrict__ cscale) // [4096]     f32
{
    __shared__ float row[IN_F];
    const int b   = blockIdx.x;
    const int tid = threadIdx.x;

    for (int i = tid; i < IN_F; i += 1024) row[i] = x[b * IN_F + i];
    __syncthreads();

    for (int k = 0; k < KROT; ++k) {
        const int2*  pk = (const int2*)(pairs + k * IN_F);
        const float* tk = theta + k * (IN_F / 2);
        for (int p = tid; p < IN_F / 2; p += 1024) {
            int2  ij = pk[p];
            float th = tk[p];
            float c = cosf(th), s = sinf(th);
            float a  = row[ij.x];
            float bb = row[ij.y];
            row[ij.x] = c * a - s * bb;
            row[ij.y] = s * a + c * bb;
        }
        __syncthreads();
    }

    for (int i = tid; i < IN_F; i += 1024)
        g_xr[b * IN_F + i] = row[i] * cscale[i];
}

// ---------------------------------------------------------------------------
// Kernel 2: dequant + GEMM partials. Block = (group g 0..31, jp chunk 0..13).
// Thread = (jp lane 0..127, batch-half): 8 cols x 8 batches fp32 acc (AGPRs).
// qweight words each loaded exactly once device-wide, coalesced. Partials go
// to g_part as PLAIN float4 stores (round-3 counters: atomics write through
// to HBM at 32B/op = 234.9 MB = the entire 230us -> atomics eliminated).
// ---------------------------------------------------------------------------
__global__ __launch_bounds__(256) void k_gemm(
    const int*   __restrict__ qweight, // [4096][1792] int32
    const int*   __restrict__ qzeros,  // [32][1792]   int32
    const float* __restrict__ scales)  // [32][14336]  f32
{
    __shared__ float xl[GROUP][BATCH];
    const int g   = blockIdx.x & 31;
    const int jpr = blockIdx.x >> 5;   // 0..13
    const int tid = threadIdx.x;

    // stage this K-group's activations (global-coalesced)
    for (int idx = tid; idx < GROUP * BATCH; idx += 256) {
        int kk = idx & 127, b = idx >> 7;
        xl[kk][b] = g_xr[b * IN_F + g * GROUP + kk];
    }
    __syncthreads();

    const int jp = jpr * 128 + (tid & 127);  // packed-word column, 0..1791
    const int bh = tid >> 7;                 // batch half

    const uint32_t zw = (uint32_t)qzeros[g * NJP + jp];
    const float4* sc4 = (const float4*)(scales + (size_t)g * OUT_F + jp * 8);
    float4 s0 = sc4[0], s1 = sc4[1];
    float s[8] = {s0.x, s0.y, s0.z, s0.w, s1.x, s1.y, s1.z, s1.w};
    float o[8];
#pragma unroll
    for (int c = 0; c < 8; ++c)
        o[c] = (float)((zw >> (4 * c)) & 15u) * s[c];  // zero-point * scale

    float acc[8][8];
#pragma unroll
    for (int bb = 0; bb < 8; ++bb)
#pragma unroll
        for (int c = 0; c < 8; ++c) acc[bb][c] = 0.0f;

    const int* qw = qweight + (size_t)(g * GROUP) * NJP + jp;
    for (int kk = 0; kk < GROUP; ++kk) {
        uint32_t w = (uint32_t)qw[(size_t)kk * NJP];
        float wf[8];
#pragma unroll
        for (int c = 0; c < 8; ++c)
            wf[c] = fmaf((float)((w >> (4 * c)) & 15u), s[c], -o[c]);

        // same address across the wave -> LDS broadcast, no conflicts
        const float4* xk = (const float4*)&xl[kk][bh * 8];
        float4 x0 = xk[0], x1 = xk[1];
        float  xv[8] = {x0.x, x0.y, x0.z, x0.w, x1.x, x1.y, x1.z, x1.w};
#pragma unroll
        for (int bb = 0; bb < 8; ++bb)
#pragma unroll
            for (int c = 0; c < 8; ++c)
                acc[bb][c] = fmaf(xv[bb], wf[c], acc[bb][c]);
    }

    // plain stores: lane jp covers bytes [32jp, 32jp+32) of each row ->
    // wave covers a contiguous 2KB span, fully coalesced.
    float* pp = g_part + ((size_t)g * BATCH + bh * 8) * OUT_F + (size_t)jp * 8;
#pragma unroll
    for (int bb = 0; bb < 8; ++bb) {
        *(float4*)(pp + (size_t)bb * OUT_F)     = *(float4*)&acc[bb][0];
        *(float4*)(pp + (size_t)bb * OUT_F + 4) = *(float4*)&acc[bb][4];
    }
}

// ---------------------------------------------------------------------------
// Kernel 3: reduce 32 K-split partials -> d_out. One float4 per thread.
// ---------------------------------------------------------------------------
__global__ __launch_bounds__(256) void k_reduce(float* __restrict__ out)
{
    const int t = blockIdx.x * 256 + threadIdx.x;   // 0..57343
    const size_t j = (size_t)t * 4;                 // within [0, 16*14336)
    float4 s = {0.f, 0.f, 0.f, 0.f};
#pragma unroll 8
    for (int g = 0; g < NG; ++g) {
        float4 p = *(const float4*)(g_part + (size_t)g * BATCH * OUT_F + j);
        s.x += p.x; s.y += p.y; s.z += p.z; s.w += p.w;
    }
    *(float4*)(out + j) = s;
}

extern "C" void kernel_launch(void* const* d_in, const int* in_sizes, int n_in,
                              void* d_out, int out_size, void* d_ws, size_t ws_size,
                              hipStream_t stream) {
    const float* x       = (const float*)d_in[0];
    const float* theta   = (const float*)d_in[1];
    const int*   pairs   = (const int*)d_in[2];
    const float* cscale  = (const float*)d_in[3];
    const int*   qweight = (const int*)d_in[4];
    const int*   qzeros  = (const int*)d_in[5];
    const float* scales  = (const float*)d_in[6];
    float*       out     = (float*)d_out;
    (void)d_ws; (void)ws_size;

    k_rotate<<<16, 1024, 0, stream>>>(x, theta, pairs, cscale);
    k_gemm<<<448, 256, 0, stream>>>(qweight, qzeros, scales);
    k_reduce<<<(BATCH * OUT_F) / (256 * 4), 256, 0, stream>>>(out);
}

// Round 5
// 129.947 us; speedup vs baseline: 2.4199x; 1.1001x over previous
//
#include <hip/hip_runtime.h>
#include <cstdint>

#define IN_F   4096
#define OUT_F  14336
#define GROUP  128
#define KROT   8
#define BATCH  16
#define NJP    (OUT_F / 8)    // 1792 packed words per weight row
#define NG     (IN_F / GROUP) // 32 groups

// Module-scope scratch (no d_ws dependence; fully rewritten every call).
__device__ float g_xr[BATCH * IN_F];          // rotated activations
__device__ float g_part[NG * BATCH * OUT_F];  // 29.4 MB K-split partials

// ---------------------------------------------------------------------------
// Kernel 1: rotation layers. One block per batch row. All pair indices and
// cos/sin values are preloaded into REGISTERS before the layer loop (round-4:
// 16 libm cosf/sinf per thread inside the serial layer loop on 16 blocks was
// a major hidden cost). __sincosf is safe: |theta| <~ 0.7.
// ---------------------------------------------------------------------------
__global__ __launch_bounds__(1024) void k_rotate(
    const float* __restrict__ x,      // [16][4096] f32 (fp16 promoted)
    const float* __restrict__ theta,  // [8][2048]  f32
    const int*   __restrict__ pairs,  // [8][4096]  int32
    const float* __restrict__ cscale) // [4096]     f32
{
    __shared__ float row[IN_F];
    const int b   = blockIdx.x;
    const int tid = threadIdx.x;

    // preload: 2 pair-slots per thread per layer (2048 pairs / 1024 threads)
    int2  ij0[KROT], ij1[KROT];
    float c0[KROT], s0[KROT], c1[KROT], s1[KROT];
#pragma unroll
    for (int k = 0; k < KROT; ++k) {
        const int2*  pk = (const int2*)(pairs + k * IN_F);
        const float* tk = theta + k * (IN_F / 2);
        ij0[k] = pk[tid];
        ij1[k] = pk[tid + 1024];
        __sincosf(tk[tid],        &s0[k], &c0[k]);
        __sincosf(tk[tid + 1024], &s1[k], &c1[k]);
    }

    for (int i = tid; i < IN_F; i += 1024) row[i] = x[b * IN_F + i];
    __syncthreads();

    // pairs[k] is a permutation: element sets are disjoint across threads
    // within a layer -> read-own / write-own, one barrier per layer.
#pragma unroll
    for (int k = 0; k < KROT; ++k) {
        float a0 = row[ij0[k].x], b0 = row[ij0[k].y];
        float a1 = row[ij1[k].x], b1 = row[ij1[k].y];
        row[ij0[k].x] = c0[k] * a0 - s0[k] * b0;
        row[ij0[k].y] = s0[k] * a0 + c0[k] * b0;
        row[ij1[k].x] = c1[k] * a1 - s1[k] * b1;
        row[ij1[k].y] = s1[k] * a1 + c1[k] * b1;
        __syncthreads();
    }

    for (int i = tid; i < IN_F; i += 1024)
        g_xr[b * IN_F + i] = row[i] * cscale[i];
}

// ---------------------------------------------------------------------------
// Kernel 2: dequant + GEMM partials. Block = (group g 0..31, jp chunk 0..13).
// Round-4 counters: VALUBusy 36%, occupancy 14% -> load-latency bound.
// Fix: unroll-by-8 software prefetch; 8 qweight words stay in flight while
// the previous 8 are unpacked+FMAed (~1500 cyc compute vs ~900 cyc latency).
// ---------------------------------------------------------------------------
__global__ __launch_bounds__(256) void k_gemm(
    const int*   __restrict__ qweight, // [4096][1792] int32
    const int*   __restrict__ qzeros,  // [32][1792]   int32
    const float* __restrict__ scales)  // [32][14336]  f32
{
    __shared__ float xl[GROUP][BATCH];
    const int g   = blockIdx.x & 31;
    const int jpr = blockIdx.x >> 5;   // 0..13
    const int tid = threadIdx.x;

    for (int idx = tid; idx < GROUP * BATCH; idx += 256) {
        int kk = idx & 127, b = idx >> 7;
        xl[kk][b] = g_xr[b * IN_F + g * GROUP + kk];
    }
    __syncthreads();

    const int jp = jpr * 128 + (tid & 127);  // packed-word column, 0..1791
    const int bh = tid >> 7;                 // batch half

    const uint32_t zw = (uint32_t)qzeros[g * NJP + jp];
    const float4* sc4 = (const float4*)(scales + (size_t)g * OUT_F + jp * 8);
    float4 s0 = sc4[0], s1 = sc4[1];
    float s[8] = {s0.x, s0.y, s0.z, s0.w, s1.x, s1.y, s1.z, s1.w};
    float o[8];
#pragma unroll
    for (int c = 0; c < 8; ++c)
        o[c] = (float)((zw >> (4 * c)) & 15u) * s[c];

    float acc[8][8];
#pragma unroll
    for (int bb = 0; bb < 8; ++bb)
#pragma unroll
        for (int c = 0; c < 8; ++c) acc[bb][c] = 0.0f;

    const int* qw = qweight + (size_t)(g * GROUP) * NJP + jp;

    uint32_t wn[8];
#pragma unroll
    for (int u = 0; u < 8; ++u) wn[u] = (uint32_t)qw[(size_t)u * NJP];

    for (int kk = 0; kk < GROUP; kk += 8) {
        uint32_t wc[8];
#pragma unroll
        for (int u = 0; u < 8; ++u) wc[u] = wn[u];
        if (kk + 8 < GROUP) {
#pragma unroll
            for (int u = 0; u < 8; ++u)
                wn[u] = (uint32_t)qw[(size_t)(kk + 8 + u) * NJP];
        }
#pragma unroll
        for (int u = 0; u < 8; ++u) {
            float wf[8];
#pragma unroll
            for (int c = 0; c < 8; ++c)
                wf[c] = fmaf((float)((wc[u] >> (4 * c)) & 15u), s[c], -o[c]);

            // same LDS address across the wave -> broadcast, conflict-free
            const float4* xk = (const float4*)&xl[kk + u][bh * 8];
            float4 x0 = xk[0], x1 = xk[1];
            float  xv[8] = {x0.x, x0.y, x0.z, x0.w, x1.x, x1.y, x1.z, x1.w};
#pragma unroll
            for (int bb = 0; bb < 8; ++bb)
#pragma unroll
                for (int c = 0; c < 8; ++c)
                    acc[bb][c] = fmaf(xv[bb], wf[c], acc[bb][c]);
        }
    }

    float* pp = g_part + ((size_t)g * BATCH + bh * 8) * OUT_F + (size_t)jp * 8;
#pragma unroll
    for (int bb = 0; bb < 8; ++bb) {
        *(float4*)(pp + (size_t)bb * OUT_F)     = *(float4*)&acc[bb][0];
        *(float4*)(pp + (size_t)bb * OUT_F + 4) = *(float4*)&acc[bb][4];
    }
}

// ---------------------------------------------------------------------------
// Kernel 3: reduce 32 K-split partials -> d_out. One float4 per thread,
// fully unrolled (32 independent dwordx4 loads in flight).
// ---------------------------------------------------------------------------
__global__ __launch_bounds__(128) void k_reduce(float* __restrict__ out)
{
    const int t = blockIdx.x * 128 + threadIdx.x;   // 0..57343
    const size_t j = (size_t)t * 4;
    float4 s = {0.f, 0.f, 0.f, 0.f};
#pragma unroll
    for (int g = 0; g < NG; ++g) {
        float4 p = *(const float4*)(g_part + (size_t)g * BATCH * OUT_F + j);
        s.x += p.x; s.y += p.y; s.z += p.z; s.w += p.w;
    }
    *(float4*)(out + j) = s;
}

extern "C" void kernel_launch(void* const* d_in, const int* in_sizes, int n_in,
                              void* d_out, int out_size, void* d_ws, size_t ws_size,
                              hipStream_t stream) {
    const float* x       = (const float*)d_in[0];
    const float* theta   = (const float*)d_in[1];
    const int*   pairs   = (const int*)d_in[2];
    const float* cscale  = (const float*)d_in[3];
    const int*   qweight = (const int*)d_in[4];
    const int*   qzeros  = (const int*)d_in[5];
    const float* scales  = (const float*)d_in[6];
    float*       out     = (float*)d_out;
    (void)d_ws; (void)ws_size;

    k_rotate<<<16, 1024, 0, stream>>>(x, theta, pairs, cscale);
    k_gemm<<<448, 256, 0, stream>>>(qweight, qzeros, scales);
    k_reduce<<<(BATCH * OUT_F) / (128 * 4), 128, 0, stream>>>(out);
}

// Round 6
// 110.250 us; speedup vs baseline: 2.8522x; 1.1787x over previous
//
#include <hip/hip_runtime.h>
#include <cstdint>

#define IN_F   4096
#define OUT_F  14336
#define GROUP  128
#define KROT   8
#define BATCH  16
#define NJP    1792           // packed words per weight row
#define NG     32             // quant groups

typedef __attribute__((ext_vector_type(8))) short short8;  // 8 bf16
typedef __attribute__((ext_vector_type(4))) float f32x4;

// Module-scope scratch (no d_ws dependence).
__device__ uint32_t g_xa[BATCH * IN_F / 2];    // rotated activations, bf16 pairs [16][2048]
__device__ float    g_part[4 * BATCH * OUT_F]; // 4 K-chunk fp32 partials (3.7 MB)

static __device__ __forceinline__ unsigned short f2bf(float f) {
    union { float f; uint32_t i; } v; v.f = f;
    uint32_t u = v.i;
    uint32_t r = u + 0x7FFFu + ((u >> 16) & 1u);  // RNE
    return (unsigned short)(r >> 16);
}

// ---------------------------------------------------------------------------
// Kernel 1: rotation layers (unchanged core) + bf16-pack output for MFMA A.
// ---------------------------------------------------------------------------
__global__ __launch_bounds__(1024) void k_rotate(
    const float* __restrict__ x,      // [16][4096] f32 (fp16 promoted)
    const float* __restrict__ theta,  // [8][2048]  f32
    const int*   __restrict__ pairs,  // [8][4096]  int32
    const float* __restrict__ cscale) // [4096]     f32
{
    __shared__ float row[IN_F];
    const int b   = blockIdx.x;
    const int tid = threadIdx.x;

    int2  ij0[KROT], ij1[KROT];
    float c0[KROT], s0[KROT], c1[KROT], s1[KROT];
#pragma unroll
    for (int k = 0; k < KROT; ++k) {
        const int2*  pk = (const int2*)(pairs + k * IN_F);
        const float* tk = theta + k * (IN_F / 2);
        ij0[k] = pk[tid];
        ij1[k] = pk[tid + 1024];
        __sincosf(tk[tid],        &s0[k], &c0[k]);
        __sincosf(tk[tid + 1024], &s1[k], &c1[k]);
    }

    for (int i = tid; i < IN_F; i += 1024) row[i] = x[b * IN_F + i];
    __syncthreads();

#pragma unroll
    for (int k = 0; k < KROT; ++k) {
        float a0 = row[ij0[k].x], b0 = row[ij0[k].y];
        float a1 = row[ij1[k].x], b1 = row[ij1[k].y];
        row[ij0[k].x] = c0[k] * a0 - s0[k] * b0;
        row[ij0[k].y] = s0[k] * a0 + c0[k] * b0;
        row[ij1[k].x] = c1[k] * a1 - s1[k] * b1;
        row[ij1[k].y] = s1[k] * a1 + c1[k] * b1;
        __syncthreads();
    }

    // pack to bf16 pairs: g_xa[b][i] = {row[2i], row[2i+1]}
    for (int i = tid; i < IN_F / 2; i += 1024) {
        float v0 = row[2 * i]     * cscale[2 * i];
        float v1 = row[2 * i + 1] * cscale[2 * i + 1];
        g_xa[b * (IN_F / 2) + i] =
            (uint32_t)f2bf(v0) | ((uint32_t)f2bf(v1) << 16);
    }
}

// ---------------------------------------------------------------------------
// Kernel 2: MFMA dequant-GEMM. Block = (n-block 0..111 of 128 cols, K-chunk
// 0..3 of 1024). Per 128-k group: stage dequantized (iw-iz) as bf16 into an
// XOR-swizzled LDS tile [n_loc][k-octet], 4x mfma_16x16x32 per n-tile into a
// fresh acc, then one scale-FMA per group into the fp32 master acc (scales
// are group-constant -> hoisted out of the per-weight path entirely).
// ---------------------------------------------------------------------------
__global__ __launch_bounds__(256) void k_gemm(
    const int*   __restrict__ qweight, // [4096][1792] int32
    const int*   __restrict__ qzeros,  // [32][1792]   int32
    const float* __restrict__ scales)  // [32][14336]  f32
{
    // [128 n][16 k-octet cells of 16B + 1 pad cell] -> 34816 B
    __shared__ uint4 ldsb[128 * 17];

    const int tid   = threadIdx.x;
    const int bn    = blockIdx.x % 112;
    const int bk    = blockIdx.x / 112;       // K-chunk 0..3
    const int n0    = bn * 128;
    const int jp0   = n0 >> 3;                // 16 words per block row
    const int jp    = tid & 15;               // word lane 0..15
    const int koct  = tid >> 4;               // k-octet 0..15
    const int lane  = tid & 63;
    const int wv    = tid >> 6;               // wave 0..3
    const int mrow  = lane & 15;
    const int quad  = lane >> 4;
    const int xsw   = koct ^ (jp & 7);        // swizzled write k-octet

    f32x4 m0 = {0.f, 0.f, 0.f, 0.f};
    f32x4 m1 = {0.f, 0.f, 0.f, 0.f};

    const int nl0 = wv * 32 + mrow;           // n-tile 0 local col
    const int nl1 = nl0 + 16;                 // n-tile 1 local col
    const int sw0 = (nl0 >> 3) & 7;           // read swizzle keys
    const int sw1 = (nl1 >> 3) & 7;

    for (int st = 0; st < 8; ++st) {
        const int g   = bk * 8 + st;          // global quant group
        const int kr0 = g * GROUP + koct * 8;

        // load 8k x 8n word strip (per k-row the block reads 64B contiguous)
        uint32_t wvv[8];
#pragma unroll
        for (int i = 0; i < 8; ++i)
            wvv[i] = (uint32_t)qweight[(size_t)(kr0 + i) * NJP + jp0 + jp];
        const uint32_t zw = (uint32_t)qzeros[(size_t)g * NJP + jp0 + jp];

        // dequant to (iw - iz) bf16 col-strips -> LDS [n][k] (swizzled)
#pragma unroll
        for (int c = 0; c < 8; ++c) {
            const int iz = (int)((zw >> (4 * c)) & 15u);
            uint4 cell;
            uint32_t pk[4];
#pragma unroll
            for (int h = 0; h < 4; ++h) {
                union { float f; uint32_t u; } a, b;
                a.f = (float)((int)((wvv[2 * h]     >> (4 * c)) & 15u) - iz);
                b.f = (float)((int)((wvv[2 * h + 1] >> (4 * c)) & 15u) - iz);
                pk[h] = (a.u >> 16) | (b.u & 0xFFFF0000u);  // exact bf16 pack
            }
            cell.x = pk[0]; cell.y = pk[1]; cell.z = pk[2]; cell.w = pk[3];
            ldsb[(jp * 8 + c) * 17 + xsw] = cell;
        }
        __syncthreads();

        // 4 k-tiles of mfma_f32_16x16x32_bf16 into a fresh group acc
        f32x4 ga = {0.f, 0.f, 0.f, 0.f};
        f32x4 gb = {0.f, 0.f, 0.f, 0.f};
        const uint32_t* ap = g_xa + mrow * (IN_F / 2)
                           + ((bk * 1024 + st * 128 + quad * 8) >> 1);
#pragma unroll
        for (int kt = 0; kt < 4; ++kt) {
            union { uint4 q; short8 s; } af, b0, b1;
            af.q = *(const uint4*)(ap + kt * 16);   // A[m=mrow][k0+quad*8 ..+8]
            const int ko = kt * 4 + quad;
            b0.q = ldsb[nl0 * 17 + (ko ^ sw0)];     // B[k][n=nl0]
            b1.q = ldsb[nl1 * 17 + (ko ^ sw1)];
            ga = __builtin_amdgcn_mfma_f32_16x16x32_bf16(af.s, b0.s, ga, 0, 0, 0);
            gb = __builtin_amdgcn_mfma_f32_16x16x32_bf16(af.s, b1.s, gb, 0, 0, 0);
        }
        // fold per-group scale (one FMA per acc reg per group)
        const float s0 = scales[(size_t)g * OUT_F + n0 + nl0];
        const float s1 = scales[(size_t)g * OUT_F + n0 + nl1];
        m0 += s0 * ga;
        m1 += s1 * gb;
        __syncthreads();
    }

    // epilogue: C/D layout col=lane&15, row=quad*4+reg
    float* pp = g_part + (size_t)bk * BATCH * OUT_F;
#pragma unroll
    for (int r = 0; r < 4; ++r) {
        const int row = quad * 4 + r;
        pp[(size_t)row * OUT_F + n0 + nl0] = m0[r];
        pp[(size_t)row * OUT_F + n0 + nl1] = m1[r];
    }
}

// ---------------------------------------------------------------------------
// Kernel 3: sum the 4 K-chunk partials -> d_out. float4 per thread.
// ---------------------------------------------------------------------------
__global__ __launch_bounds__(128) void k_reduce(float* __restrict__ out)
{
    const int t = blockIdx.x * 128 + threadIdx.x;   // 0..57343
    const size_t j = (size_t)t * 4;
    float4 a = *(const float4*)(g_part + j);
    float4 b = *(const float4*)(g_part + (size_t)BATCH * OUT_F + j);
    float4 c = *(const float4*)(g_part + (size_t)2 * BATCH * OUT_F + j);
    float4 d = *(const float4*)(g_part + (size_t)3 * BATCH * OUT_F + j);
    float4 s;
    s.x = (a.x + b.x) + (c.x + d.x);
    s.y = (a.y + b.y) + (c.y + d.y);
    s.z = (a.z + b.z) + (c.z + d.z);
    s.w = (a.w + b.w) + (c.w + d.w);
    *(float4*)(out + j) = s;
}

extern "C" void kernel_launch(void* const* d_in, const int* in_sizes, int n_in,
                              void* d_out, int out_size, void* d_ws, size_t ws_size,
                              hipStream_t stream) {
    const float* x       = (const float*)d_in[0];
    const float* theta   = (const float*)d_in[1];
    const int*   pairs   = (const int*)d_in[2];
    const float* cscale  = (const float*)d_in[3];
    const int*   qweight = (const int*)d_in[4];
    const int*   qzeros  = (const int*)d_in[5];
    const float* scales  = (const float*)d_in[6];
    float*       out     = (float*)d_out;
    (void)d_ws; (void)ws_size;

    k_rotate<<<16, 1024, 0, stream>>>(x, theta, pairs, cscale);
    k_gemm<<<448, 256, 0, stream>>>(qweight, qzeros, scales);
    k_reduce<<<(BATCH * OUT_F) / (128 * 4), 128, 0, stream>>>(out);
}